// Round 6
// baseline (530.990 us; speedup 1.0000x reference)
//
#include <hip/hip_runtime.h>

#define P_PTS 131072
#define CDIM  512
#define MCAP  1024
#define TLEN  262144
#define PORIG 163840

typedef unsigned short u16;
typedef unsigned char  u8;
typedef __attribute__((ext_vector_type(8))) short short8;
typedef __attribute__((ext_vector_type(4))) float f32x4;
typedef __attribute__((ext_vector_type(8))) int int8v;
typedef __attribute__((ext_vector_type(4))) int int4v;

union V32 { int8v v8; int4v v4[2]; };   // 32-byte operand: 2x16B loads, 1 MFMA reg tuple

__device__ __forceinline__ u16 f2bf(float f) {
    unsigned u = __float_as_uint(f);
    unsigned r = (u + 0x7FFFu + ((u >> 16) & 1u)) >> 16;
    return (u16)r;
}
// OCP e4m3 decode: normals AND subnormals via f32-subnormal trick
__device__ __forceinline__ float d_e4m3(unsigned x) {
    float f = __uint_as_float((x & 0x7Fu) << 20) * 0x1p120f;
    return __uint_as_float(__float_as_uint(f) | ((x & 0x80u) << 24));
}
__device__ __forceinline__ void ld16(const void* g, void* l) {
    __builtin_amdgcn_global_load_lds(
        (const __attribute__((address_space(1))) void*)g,
        (__attribute__((address_space(3))) void*)l, 16, 0, 0);
}

// feats8 layout (MFMA-A fragment order, verified in R2: absmax 0.125):
//   F(row,c) = (row>>4)*8192 + (c>>7)*2048 + ((c>>5)&3)*512 + (row&15)*32 + (c&31)
// fragment read: lane l gets A[R0+(l&15)][kk*128+(l>>4)*32 .. +32] at
//   R0*512 + kk*2048 + l*32  (contiguous 2 KB per 16-row chunk)

// ---- fused: gather+normalize (blocks 0..32767, swizzled feats8 via LDS
//      transpose), cap cast bf16 + ptom scatter (32768..33279), lse_sum zero
//      (33280..33791), B pre-swizzle (33792..33919)
__global__ __launch_bounds__(256) void gather_prep(
    const float* __restrict__ adapter, const int* __restrict__ v2p,
    const float* __restrict__ cap, const int* __restrict__ oidx,
    u8* __restrict__ feats8, u16* __restrict__ capb, u8* __restrict__ Bswz,
    int* __restrict__ ptom, float* __restrict__ lse_sum) {
    __shared__ __align__(16) u8 sm[4 * 544];
    int b = blockIdx.x, tid = threadIdx.x;
    if (b < 32768) {
        int w = tid >> 6, lane = tid & 63;
        int p = b * 4 + w;
        int vrow = v2p[p];
        const float4* src = (const float4*)(adapter + (size_t)vrow * CDIM);
        float4 x0 = src[lane * 2];
        float4 x1 = src[lane * 2 + 1];
        float ss = x0.x*x0.x + x0.y*x0.y + x0.z*x0.z + x0.w*x0.w
                 + x1.x*x1.x + x1.y*x1.y + x1.z*x1.z + x1.w*x1.w;
        #pragma unroll
        for (int off = 32; off >= 1; off >>= 1) ss += __shfl_xor(ss, off, 64);
        float inv = 1.0f / fmaxf(sqrtf(ss), 1e-12f);
        int lo = __builtin_amdgcn_cvt_pk_fp8_f32(x0.x*inv, x0.y*inv, 0, false);
        lo = __builtin_amdgcn_cvt_pk_fp8_f32(x0.z*inv, x0.w*inv, lo, true);
        int hi = __builtin_amdgcn_cvt_pk_fp8_f32(x1.x*inv, x1.y*inv, 0, false);
        hi = __builtin_amdgcn_cvt_pk_fp8_f32(x1.z*inv, x1.w*inv, hi, true);
        uint2 wv; wv.x = (unsigned)lo; wv.y = (unsigned)hi;
        *(uint2*)(sm + w * 544 + lane * 8) = wv;     // row w, bytes lane*8..+8
        __syncthreads();
        // write out in fragment order: 16 chunks (kk,q) x 128 B contiguous
        int chunk = tid >> 4, inner = tid & 15;
        int kk = chunk >> 2, q = chunk & 3, rr = inner >> 2;
        uint2 v = *(const uint2*)(sm + rr * 544 + kk * 128 + q * 32 + (inner & 3) * 8);
        *(uint2*)(feats8 + (size_t)(b >> 2) * 8192 + kk * 2048 + q * 512
                         + (b & 3) * 128 + inner * 8) = v;
    } else if (b < 33280) {
        int t = (b - 32768) * 256 + tid;       // [0, 131072)
        int i = t * 4;
        float4 v = *(const float4*)(cap + i);
        u16* o = capb + i;
        o[0] = f2bf(v.x); o[1] = f2bf(v.y); o[2] = f2bf(v.z); o[3] = f2bf(v.w);
        atomicMax(&ptom[oidx[t]], t);          // last-write-wins == max (t increasing)
    } else if (b < 33792) {
        int j = (b - 33280) * 256 + tid;       // [0, 131072)
        lse_sum[j] = 0.0f;
    } else {
        // B pre-swizzle into MFMA fragment order: granule g2 (16 B) ->
        // c=g2&1, lane=(g2>>1)&63, j=(g2>>7)&3, kk=(g2>>9)&3, wn=(g2>>11)&1, c0=g2>>12
        int g2 = (b - 33792) * 256 + tid;      // [0, 32768)
        int c    = g2 & 1;
        int lane = (g2 >> 1) & 63;
        int j    = (g2 >> 7) & 3;
        int kk   = (g2 >> 9) & 3;
        int wn   = (g2 >> 11) & 1;
        int c0   = g2 >> 12;
        int col  = c0 * 128 + wn * 64 + j * 16 + (lane & 15);
        int kb   = kk * 128 + (lane >> 4) * 32 + c * 16;
        const float* s = cap + (size_t)col * CDIM + kb;
        unsigned w4[4];
        #pragma unroll
        for (int u = 0; u < 4; ++u) {
            int p = __builtin_amdgcn_cvt_pk_fp8_f32(s[u*4+0], s[u*4+1], 0, false);
            p = __builtin_amdgcn_cvt_pk_fp8_f32(s[u*4+2], s[u*4+3], p, true);
            w4[u] = (unsigned)p;
        }
        *(uint4*)(Bswz + (size_t)g2 * 16) = *(uint4*)w4;
    }
}

// ---- heavy GEMM: MX-fp8 K=128 MFMA, 128x128 tiles (R0 skeleton).
//      A double-buffered in LDS (2x16 KB), staged EARLY each iter via
//      global_load_lds from fragment-order feats8 (WAVE-UNIFORM LDS dest;
//      HW adds lane*16). ONE __syncthreads per iter at the END so the vmcnt
//      drain is covered by the whole compute phase. B direct-from-global in
//      pre-swizzled fragment order. 4 blocks/CU (32 KB LDS, <=128 VGPR) ->
//      wave-TLP hides B latency. Epilogue = R0's verified exp/shfl/atomicAdd.
//      Tail blocks (>=8192) do make_rows.
__global__ __launch_bounds__(256, 4) void lse_gemm(
    const u8* __restrict__ feats8, const u8* __restrict__ Bswz,
    const float* __restrict__ lsc, float* __restrict__ lse_sum,
    const int* __restrict__ ctpm, const int* __restrict__ ptom,
    unsigned* __restrict__ rows) {
    if (blockIdx.x >= 8192) {                  // make_rows tail
        int t = (blockIdx.x - 8192) * 256 + threadIdx.x;
        int g = ptom[ctpm[t]];
        rows[t] = (g < 0) ? ((unsigned)(g + P_PTS) | 0x80000000u) : (unsigned)g;
        return;
    }
    __shared__ __align__(16) u8 As[2][16384];
    const int tid  = threadIdx.x;
    const int wave = tid >> 6;
    const int lane = tid & 63;
    const unsigned id = blockIdx.x;
    const int c0   = (int)((id >> 3) & 7u);
    const int rt   = (int)((id & 7u) + 8u * (id >> 6));   // row-tile 0..1023
    const int row0 = rt * 128;
    const int wm   = (wave >> 1) * 64;
    const int wn1  = (wave & 1);
    const float sf = __expf(lsc[0]);

    // stage geometry: wave w moves 4 KB of the 16 KB kk-slice.
    // LDS dest (wave-uniform; HW adds lane*16): As[BUF] + w*4096 + u*1024
    // global src: (rt*8 + w*2 + (u>>1))*8192 + kk*2048 + (u&1)*1024 + lane*16
    const u8* gAb = feats8 + ((size_t)rt * 8 + wave * 2) * 8192 + lane * 16;
    #define STAGE(KK, BUF)                                                    \
        {   u8* d = As[BUF] + wave * 4096;                                    \
            _Pragma("unroll")                                                 \
            for (int u = 0; u < 4; ++u)                                       \
                ld16(gAb + (size_t)(u >> 1) * 8192 + (KK) * 2048 + (u & 1) * 1024, \
                     d + u * 1024); }

    // A frag (i) in buf: As[buf] + ((wave>>1)*4 + i)*2048 + lane*32
    const u8* rA0 = As[0] + (size_t)((wave >> 1) * 4) * 2048 + lane * 32;
    const u8* rA1 = As[1] + (size_t)((wave >> 1) * 4) * 2048 + lane * 32;
    // B frag (kk,j): Bswz + (c0*2+wn1)*32768 + kk*8192 + j*2048 + lane*32
    const u8* bw = Bswz + (size_t)(c0 * 2 + wn1) * 32768 + lane * 32;

    f32x4 acc[4][4] = {};

    STAGE(0, 0)
    __syncthreads();

    #pragma unroll
    for (int kk = 0; kk < 4; ++kk) {
        if (kk < 3) {                          // stage next tile EARLY
            if (kk & 1) { STAGE(kk + 1, 0) } else { STAGE(kk + 1, 1) }
        }
        const u8* rA = (kk & 1) ? rA1 : rA0;
        int8v bv[4];
        #pragma unroll
        for (int j = 0; j < 4; ++j) {
            int4v lo = *(const int4v*)(bw + kk * 8192 + j * 2048);
            int4v hi = *(const int4v*)(bw + kk * 8192 + j * 2048 + 16);
            bv[j][0]=lo[0]; bv[j][1]=lo[1]; bv[j][2]=lo[2]; bv[j][3]=lo[3];
            bv[j][4]=hi[0]; bv[j][5]=hi[1]; bv[j][6]=hi[2]; bv[j][7]=hi[3];
        }
        #pragma unroll
        for (int i = 0; i < 4; ++i) {
            V32 af;
            af.v4[0] = *(const int4v*)(rA + i * 2048);
            af.v4[1] = *(const int4v*)(rA + i * 2048 + 16);
            #pragma unroll
            for (int j = 0; j < 4; ++j)
                acc[i][j] = __builtin_amdgcn_mfma_scale_f32_16x16x128_f8f6f4(
                    af.v8, bv[j], acc[i][j], 0, 0, 0, 127, 0, 127); // e8m0 127 = x1.0
        }
        __syncthreads();                       // drain covered by compute above
    }

    const int m = lane & 15;
    const int q = lane >> 4;
    #pragma unroll
    for (int i = 0; i < 4; ++i) {
        float s4[4] = {0.f, 0.f, 0.f, 0.f};
        #pragma unroll
        for (int j = 0; j < 4; ++j)
            #pragma unroll
            for (int r = 0; r < 4; ++r)
                s4[r] += __expf(acc[i][j][r] * sf - sf);
        #pragma unroll
        for (int off = 8; off >= 1; off >>= 1)
            #pragma unroll
            for (int r = 0; r < 4; ++r)
                s4[r] += __shfl_xor(s4[r], off, 64);
        if (m == 0) {
            int rbase = row0 + wm + i * 16 + q * 4;
            #pragma unroll
            for (int r = 0; r < 4; ++r)
                atomicAdd(&lse_sum[rbase + r], s4[r]);
        }
    }
    #undef STAGE
}

__device__ __forceinline__ int lower_bound(const int* __restrict__ a, int n, int key) {
    int lo = 0, hi = n;
    while (lo < hi) { int mid = (lo + hi) >> 1; if (a[mid] < key) lo = mid + 1; else hi = mid; }
    return lo;
}

// ---- per-segment: Fb[s] = sum feats rows (bf16), L[s] = sum log lse_sum, counts.
//      feats8 is fragment-swizzled: lane reads 8 B at a fixed (row-independent)
//      channel slot chb = (lane>>4)*128 + ((lane>>2)&3)*32 + (lane&3)*8 ----
__global__ __launch_bounds__(1024) void seg_reduce(
    const u8* __restrict__ feats8, const float* __restrict__ lse_sum,
    const unsigned* __restrict__ rows, const int* __restrict__ seg,
    const float* __restrict__ lsc,
    u16* __restrict__ Fb, float* __restrict__ Lout, float* __restrict__ realn) {
    int s = blockIdx.x;
    int tid = threadIdx.x, wave = tid >> 6, lane = tid & 63;
    int start = lower_bound(seg, TLEN, s);
    int end   = lower_bound(seg, TLEN, s + 1);
    const int loff = (lane >> 4) * 2048 + ((lane >> 2) & 3) * 512 + (lane & 3) * 8;
    const int chb  = (lane >> 4) * 128  + ((lane >> 2) & 3) * 32  + (lane & 3) * 8;
    float a[8] = {0,0,0,0,0,0,0,0};
    float Lacc = 0.f; int inv = 0;
    int r = start + wave;
    for (; r + 16 < end; r += 32) {
        unsigned p0 = rows[r], p1 = rows[r + 16];
        int r0 = (int)(p0 & 0x7FFFFFFFu), r1 = (int)(p1 & 0x7FFFFFFFu);
        uint2 v0 = *(const uint2*)(feats8 + (size_t)(r0 >> 4) * 8192 + (r0 & 15) * 32 + loff);
        uint2 v1 = *(const uint2*)(feats8 + (size_t)(r1 >> 4) * 8192 + (r1 & 15) * 32 + loff);
        if (lane == 0) {
            inv += (int)(p0 >> 31) + (int)(p1 >> 31);
            Lacc += __logf(lse_sum[r0]) + __logf(lse_sum[r1]);
        }
        a[0] += d_e4m3(v0.x);       a[1] += d_e4m3(v0.x >> 8);
        a[2] += d_e4m3(v0.x >> 16); a[3] += d_e4m3(v0.x >> 24);
        a[4] += d_e4m3(v0.y);       a[5] += d_e4m3(v0.y >> 8);
        a[6] += d_e4m3(v0.y >> 16); a[7] += d_e4m3(v0.y >> 24);
        a[0] += d_e4m3(v1.x);       a[1] += d_e4m3(v1.x >> 8);
        a[2] += d_e4m3(v1.x >> 16); a[3] += d_e4m3(v1.x >> 24);
        a[4] += d_e4m3(v1.y);       a[5] += d_e4m3(v1.y >> 8);
        a[6] += d_e4m3(v1.y >> 16); a[7] += d_e4m3(v1.y >> 24);
    }
    if (r < end) {
        unsigned p0 = rows[r];
        int r0 = (int)(p0 & 0x7FFFFFFFu);
        uint2 v0 = *(const uint2*)(feats8 + (size_t)(r0 >> 4) * 8192 + (r0 & 15) * 32 + loff);
        if (lane == 0) { inv += (int)(p0 >> 31); Lacc += __logf(lse_sum[r0]); }
        a[0] += d_e4m3(v0.x);       a[1] += d_e4m3(v0.x >> 8);
        a[2] += d_e4m3(v0.x >> 16); a[3] += d_e4m3(v0.x >> 24);
        a[4] += d_e4m3(v0.y);       a[5] += d_e4m3(v0.y >> 8);
        a[6] += d_e4m3(v0.y >> 16); a[7] += d_e4m3(v0.y >> 24);
    }
    __shared__ float pF[16][512];
    __shared__ float pL[16];
    __shared__ int   pI[16];
    #pragma unroll
    for (int u = 0; u < 8; ++u) pF[wave][chb + u] = a[u];
    if (lane == 0) { pL[wave] = Lacc; pI[wave] = inv; }
    __syncthreads();
    if (tid < 512) {
        float f = 0.f;
        #pragma unroll
        for (int w = 0; w < 16; ++w) f += pF[w][tid];
        Fb[(size_t)s * CDIM + tid] = f2bf(f);
    }
    if (tid == 0) {
        float cnt = (float)(end - start);
        float Ls = 0.f; int ninv = 0;
        #pragma unroll
        for (int w = 0; w < 16; ++w) { Ls += pL[w]; ninv += pI[w]; }
        realn[s] = cnt - (float)ninv;
        Lout[s] = Ls + __expf(lsc[0]) * cnt;   // each lse = sf + log(sum)
    }
}

// ---- pooled[s,m] = (sf*Fb[s].capb[m] - L[s]) * (1/real or 0); 64x64 bf16 MFMA
//      NO LDS, NO BARRIERS: fragments loaded direct from row-major Fb/capb
//      (both 1 MB, L2-resident). ----
__global__ __launch_bounds__(256) void pooled_gemm(
    const u16* __restrict__ Fb, const u16* __restrict__ capb,
    const float* __restrict__ Lout, const float* __restrict__ realn,
    const float* __restrict__ lsc, float* __restrict__ out) {
    const int tid  = threadIdx.x;
    const int wave = tid >> 6;
    const int lane = tid & 63;
    const int col0 = blockIdx.x * 64;   // captions
    const int row0 = blockIdx.y * 64;   // segments
    const int wm = (wave >> 1) * 32;
    const int wn = (wave & 1) * 32;
    const float sf = __expf(lsc[0]);
    f32x4 acc[2][2] = {};
    const int mrow = lane & 15;
    const int quad = lane >> 4;
    // fragment for 16x16x32 bf16: lane (mrow,quad) holds row[k0+quad*8 .. +8]
    const u16* gA = Fb   + (size_t)(row0 + wm + mrow) * CDIM + quad * 8;
    const u16* gB = capb + (size_t)(col0 + wn + mrow) * CDIM + quad * 8;
    #pragma unroll
    for (int k0 = 0; k0 < CDIM; k0 += 32) {
        short8 af[2], bfr[2];
        #pragma unroll
        for (int i = 0; i < 2; ++i)
            af[i]  = *(const short8*)(gA + (size_t)(i * 16) * CDIM + k0);
        #pragma unroll
        for (int j = 0; j < 2; ++j)
            bfr[j] = *(const short8*)(gB + (size_t)(j * 16) * CDIM + k0);
        #pragma unroll
        for (int i = 0; i < 2; ++i)
            #pragma unroll
            for (int j = 0; j < 2; ++j)
                acc[i][j] = __builtin_amdgcn_mfma_f32_16x16x32_bf16(
                    af[i], bfr[j], acc[i][j], 0, 0, 0);
    }
    #pragma unroll
    for (int i = 0; i < 2; ++i) {
        #pragma unroll
        for (int r = 0; r < 4; ++r) {
            int s = row0 + wm + i * 16 + quad * 4 + r;
            float rn = realn[s];
            float dn = rn > 0.f ? 1.0f / rn : 0.0f;
            float L = Lout[s];
            #pragma unroll
            for (int j = 0; j < 2; ++j) {
                int mc = col0 + wn + j * 16 + mrow;
                out[(size_t)s * MCAP + mc] = (sf * acc[i][j][r] - L) * dn;
            }
        }
    }
    if (col0 == 0 && tid < 64) {
        int s = row0 + tid;
        float rv = realn[s];
        out[MCAP * MCAP + s] = rv;
        out[MCAP * MCAP + MCAP + s] = (rv > 0.f) ? 1.0f : 0.0f;
    }
}

extern "C" void kernel_launch(void* const* d_in, const int* in_sizes, int n_in,
                              void* d_out, int out_size, void* d_ws, size_t ws_size,
                              hipStream_t stream) {
    const float* adapter = (const float*)d_in[0];
    const float* cap     = (const float*)d_in[1];
    const float* lsc     = (const float*)d_in[2];
    const int*   v2p     = (const int*)d_in[3];
    const int*   oidx    = (const int*)d_in[4];
    const int*   ctpm    = (const int*)d_in[5];
    const int*   seg     = (const int*)d_in[6];
    float* out = (float*)d_out;

    char* ws = (char*)d_ws;
    u8*       feats8  = (u8*)(ws);                                // 67,108,864 B
    u16*      capb    = (u16*)(ws + 67108864);                    //  1,048,576 B
    u8*       Bswz    = (u8*)(ws + 68157440);                     //    524,288 B
    float*    lse_sum = (float*)(ws + 68681728);                  //    524,288 B
    int*      ptom    = (int*)(ws + 69206016);                    //    655,360 B
    unsigned* rows    = (unsigned*)(ws + 69861376);               //  1,048,576 B
    u16*      Fb      = (u16*)(ws + 70909952);                    //  1,048,576 B
    float*    Lout    = (float*)(ws + 71958528);                  //      4,096 B
    float*    realn   = (float*)(ws + 71962624);                  //      4,096 B

    hipMemsetAsync(ptom, 0xFF, (size_t)PORIG * 4, stream);        // -1

    gather_prep<<<33920, 256, 0, stream>>>(adapter, v2p, cap, oidx,
                                           feats8, capb, Bswz, ptom, lse_sum);
    lse_gemm<<<8192 + TLEN / 256, 256, 0, stream>>>(feats8, Bswz, lsc, lse_sum,
                                                    ctpm, ptom, rows);
    seg_reduce<<<MCAP, 1024, 0, stream>>>(feats8, lse_sum, rows, seg, lsc, Fb, Lout, realn);
    pooled_gemm<<<dim3(MCAP / 64, MCAP / 64), 256, 0, stream>>>(Fb, capb, Lout, realn, lsc, out);
}

// Round 7
// 413.128 us; speedup vs baseline: 1.2853x; 1.2853x over previous
//
#include <hip/hip_runtime.h>

#define P_PTS 131072
#define CDIM  512
#define MCAP  1024
#define TLEN  262144
#define PORIG 163840

typedef unsigned short u16;
typedef unsigned char  u8;
typedef __attribute__((ext_vector_type(8))) short short8;
typedef __attribute__((ext_vector_type(4))) float f32x4;
typedef __attribute__((ext_vector_type(8))) int int8v;
typedef __attribute__((ext_vector_type(4))) int int4v;

union V32 { int8v v8; int4v v4[2]; };   // 32-byte operand: 2x16B loads, 1 MFMA reg tuple

__device__ __forceinline__ u16 f2bf(float f) {
    unsigned u = __float_as_uint(f);
    unsigned r = (u + 0x7FFFu + ((u >> 16) & 1u)) >> 16;
    return (u16)r;
}
// OCP e4m3 decode: normals AND subnormals via f32-subnormal trick
__device__ __forceinline__ float d_e4m3(unsigned x) {
    float f = __uint_as_float((x & 0x7Fu) << 20) * 0x1p120f;
    return __uint_as_float(__float_as_uint(f) | ((x & 0x80u) << 24));
}
__device__ __forceinline__ void ld16(const void* g, void* l) {
    __builtin_amdgcn_global_load_lds(
        (const __attribute__((address_space(1))) void*)g,
        (__attribute__((address_space(3))) void*)l, 16, 0, 0);
}

// feats8 layout (MFMA-A fragment order + bank swizzle):
//   chunk(rowblk=row>>4, kk=c>>7) of 2048 B; within-chunk linear offset
//   o = ((c>>5)&3)*512 + (row&15)*32 + (c&31); STORED at o ^ (((o>>8)&7)<<4).
//   The XOR spreads the ds_read_b128 pattern (lane*32 + h*16) across all 8
//   16B slot classes -> conflict-free (8 lanes/slot-class). Staging to LDS is
//   a verbatim linear copy, so the same XOR'd read address works in LDS;
//   seg_reduce applies the same XOR on its global reads.

// ---- fused: gather+normalize (blocks 0..32767, swizzled feats8 via LDS
//      transpose), cap cast bf16 + ptom scatter (32768..33279), lse_sum zero
//      (33280..33791), B pre-swizzle (33792..33919)
__global__ __launch_bounds__(256) void gather_prep(
    const float* __restrict__ adapter, const int* __restrict__ v2p,
    const float* __restrict__ cap, const int* __restrict__ oidx,
    u8* __restrict__ feats8, u16* __restrict__ capb, u8* __restrict__ Bswz,
    int* __restrict__ ptom, float* __restrict__ lse_sum) {
    __shared__ __align__(16) u8 sm[4 * 544];
    int b = blockIdx.x, tid = threadIdx.x;
    if (b < 32768) {
        int w = tid >> 6, lane = tid & 63;
        int p = b * 4 + w;
        int vrow = v2p[p];
        const float4* src = (const float4*)(adapter + (size_t)vrow * CDIM);
        float4 x0 = src[lane * 2];
        float4 x1 = src[lane * 2 + 1];
        float ss = x0.x*x0.x + x0.y*x0.y + x0.z*x0.z + x0.w*x0.w
                 + x1.x*x1.x + x1.y*x1.y + x1.z*x1.z + x1.w*x1.w;
        #pragma unroll
        for (int off = 32; off >= 1; off >>= 1) ss += __shfl_xor(ss, off, 64);
        float inv = 1.0f / fmaxf(sqrtf(ss), 1e-12f);
        int lo = __builtin_amdgcn_cvt_pk_fp8_f32(x0.x*inv, x0.y*inv, 0, false);
        lo = __builtin_amdgcn_cvt_pk_fp8_f32(x0.z*inv, x0.w*inv, lo, true);
        int hi = __builtin_amdgcn_cvt_pk_fp8_f32(x1.x*inv, x1.y*inv, 0, false);
        hi = __builtin_amdgcn_cvt_pk_fp8_f32(x1.z*inv, x1.w*inv, hi, true);
        uint2 wv; wv.x = (unsigned)lo; wv.y = (unsigned)hi;
        *(uint2*)(sm + w * 544 + lane * 8) = wv;     // row w, bytes lane*8..+8
        __syncthreads();
        // write out in fragment order (+ bank swizzle): 16 chunks (kk,q)
        int chunk = tid >> 4, inner = tid & 15;
        int kk = chunk >> 2, q = chunk & 3, rr = inner >> 2;
        uint2 v = *(const uint2*)(sm + rr * 544 + kk * 128 + q * 32 + (inner & 3) * 8);
        int o = q * 512 + (b & 3) * 128 + inner * 8;
        o ^= ((o >> 8) & 7) << 4;                    // bank swizzle
        *(uint2*)(feats8 + (size_t)(b >> 2) * 8192 + kk * 2048 + o) = v;
    } else if (b < 33280) {
        int t = (b - 32768) * 256 + tid;       // [0, 131072)
        int i = t * 4;
        float4 v = *(const float4*)(cap + i);
        u16* o = capb + i;
        o[0] = f2bf(v.x); o[1] = f2bf(v.y); o[2] = f2bf(v.z); o[3] = f2bf(v.w);
        atomicMax(&ptom[oidx[t]], t);          // last-write-wins == max (t increasing)
    } else if (b < 33792) {
        int j = (b - 33280) * 256 + tid;       // [0, 131072)
        lse_sum[j] = 0.0f;
    } else {
        // B pre-swizzle into MFMA fragment order: granule g2 (16 B) ->
        // c=g2&1, lane=(g2>>1)&63, j=(g2>>7)&3, kk=(g2>>9)&3, wn=(g2>>11)&1, c0=g2>>12
        int g2 = (b - 33792) * 256 + tid;      // [0, 32768)
        int c    = g2 & 1;
        int lane = (g2 >> 1) & 63;
        int j    = (g2 >> 7) & 3;
        int kk   = (g2 >> 9) & 3;
        int wn   = (g2 >> 11) & 1;
        int c0   = g2 >> 12;
        int col  = c0 * 128 + wn * 64 + j * 16 + (lane & 15);
        int kb   = kk * 128 + (lane >> 4) * 32 + c * 16;
        const float* s = cap + (size_t)col * CDIM + kb;
        unsigned w4[4];
        #pragma unroll
        for (int u = 0; u < 4; ++u) {
            int p = __builtin_amdgcn_cvt_pk_fp8_f32(s[u*4+0], s[u*4+1], 0, false);
            p = __builtin_amdgcn_cvt_pk_fp8_f32(s[u*4+2], s[u*4+3], p, true);
            w4[u] = (unsigned)p;
        }
        *(uint4*)(Bswz + (size_t)g2 * 16) = *(uint4*)w4;
    }
}

// ---- heavy GEMM: MX-fp8 K=128 MFMA, 128x128 tiles.
//      A double-buffered in LDS (2x16 KB), staged EARLY each iter via
//      global_load_lds (wave-uniform dest); ONE __syncthreads per iter at the
//      END so the vmcnt drain is covered by the whole compute phase. A-reads
//      bank-conflict-free via the feats8 store-side XOR swizzle. B direct-
//      from-global pre-swizzled. Default launch bounds (NO min-waves clause:
//      R6's (256,4) forced a 64-VGPR cap -> 557 MB spill).
//      Tail blocks (>=8192) do make_rows.
__global__ __launch_bounds__(256) void lse_gemm(
    const u8* __restrict__ feats8, const u8* __restrict__ Bswz,
    const float* __restrict__ lsc, float* __restrict__ lse_sum,
    const int* __restrict__ ctpm, const int* __restrict__ ptom,
    unsigned* __restrict__ rows) {
    if (blockIdx.x >= 8192) {                  // make_rows tail
        int t = (blockIdx.x - 8192) * 256 + threadIdx.x;
        int g = ptom[ctpm[t]];
        rows[t] = (g < 0) ? ((unsigned)(g + P_PTS) | 0x80000000u) : (unsigned)g;
        return;
    }
    __shared__ __align__(16) u8 As[2][16384];
    const int tid  = threadIdx.x;
    const int wave = tid >> 6;
    const int lane = tid & 63;
    const unsigned id = blockIdx.x;
    const int c0   = (int)((id >> 3) & 7u);
    const int rt   = (int)((id & 7u) + 8u * (id >> 6));   // row-tile 0..1023
    const int row0 = rt * 128;
    const int wm   = (wave >> 1) * 64;
    const int wn1  = (wave & 1);
    const float sf = __expf(lsc[0]);

    // stage geometry: wave w moves 4 KB of the 16 KB kk-slice.
    // LDS dest (wave-uniform; HW adds lane*16): As[BUF] + w*4096 + u*1024
    const u8* gAb = feats8 + ((size_t)rt * 8 + wave * 2) * 8192 + lane * 16;
    #define STAGE(KK, BUF)                                                    \
        {   u8* d = As[BUF] + wave * 4096;                                    \
            _Pragma("unroll")                                                 \
            for (int u = 0; u < 4; ++u)                                       \
                ld16(gAb + (size_t)(u >> 1) * 8192 + (KK) * 2048 + (u & 1) * 1024, \
                     d + u * 1024); }

    // swizzled A-frag read offsets: sA = lane*32 ^ (((lane>>3)&7)<<4); the
    // second 16B half lives at sA^16 (bit-4 flip commutes with the XOR).
    const int sA = (lane * 32) ^ (((lane >> 3) & 7) << 4);
    const u8* rA0  = As[0] + (size_t)((wave >> 1) * 4) * 2048 + sA;
    const u8* rA0x = As[0] + (size_t)((wave >> 1) * 4) * 2048 + (sA ^ 16);
    const u8* rA1  = As[1] + (size_t)((wave >> 1) * 4) * 2048 + sA;
    const u8* rA1x = As[1] + (size_t)((wave >> 1) * 4) * 2048 + (sA ^ 16);
    // B frag (kk,j): Bswz + (c0*2+wn1)*32768 + kk*8192 + j*2048 + lane*32
    const u8* bw = Bswz + (size_t)(c0 * 2 + wn1) * 32768 + lane * 32;

    f32x4 acc[4][4] = {};

    STAGE(0, 0)
    __syncthreads();

    #pragma unroll
    for (int kk = 0; kk < 4; ++kk) {
        if (kk < 3) {                          // stage next tile EARLY
            if (kk & 1) { STAGE(kk + 1, 0) } else { STAGE(kk + 1, 1) }
        }
        const u8* rA  = (kk & 1) ? rA1  : rA0;
        const u8* rAx = (kk & 1) ? rA1x : rA0x;
        int8v bv[4];
        #pragma unroll
        for (int j = 0; j < 4; ++j) {
            int4v lo = *(const int4v*)(bw + kk * 8192 + j * 2048);
            int4v hi = *(const int4v*)(bw + kk * 8192 + j * 2048 + 16);
            bv[j][0]=lo[0]; bv[j][1]=lo[1]; bv[j][2]=lo[2]; bv[j][3]=lo[3];
            bv[j][4]=hi[0]; bv[j][5]=hi[1]; bv[j][6]=hi[2]; bv[j][7]=hi[3];
        }
        #pragma unroll
        for (int i = 0; i < 4; ++i) {
            V32 af;
            af.v4[0] = *(const int4v*)(rA  + i * 2048);
            af.v4[1] = *(const int4v*)(rAx + i * 2048);
            #pragma unroll
            for (int j = 0; j < 4; ++j)
                acc[i][j] = __builtin_amdgcn_mfma_scale_f32_16x16x128_f8f6f4(
                    af.v8, bv[j], acc[i][j], 0, 0, 0, 127, 0, 127); // e8m0 127 = x1.0
        }
        __syncthreads();                       // drain covered by compute above
    }

    const int m = lane & 15;
    const int q = lane >> 4;
    #pragma unroll
    for (int i = 0; i < 4; ++i) {
        float s4[4] = {0.f, 0.f, 0.f, 0.f};
        #pragma unroll
        for (int j = 0; j < 4; ++j)
            #pragma unroll
            for (int r = 0; r < 4; ++r)
                s4[r] += __expf(acc[i][j][r] * sf - sf);
        #pragma unroll
        for (int off = 8; off >= 1; off >>= 1)
            #pragma unroll
            for (int r = 0; r < 4; ++r)
                s4[r] += __shfl_xor(s4[r], off, 64);
        if (m == 0) {
            int rbase = row0 + wm + i * 16 + q * 4;
            #pragma unroll
            for (int r = 0; r < 4; ++r)
                atomicAdd(&lse_sum[rbase + r], s4[r]);
        }
    }
    #undef STAGE
}

__device__ __forceinline__ int lower_bound(const int* __restrict__ a, int n, int key) {
    int lo = 0, hi = n;
    while (lo < hi) { int mid = (lo + hi) >> 1; if (a[mid] < key) lo = mid + 1; else hi = mid; }
    return lo;
}

// ---- per-segment: Fb[s] = sum feats rows (bf16), L[s] = sum log lse_sum, counts.
//      feats8 reads apply the same store-side XOR swizzle; lane->channel
//      ownership unchanged (chb as before). ----
__global__ __launch_bounds__(1024) void seg_reduce(
    const u8* __restrict__ feats8, const float* __restrict__ lse_sum,
    const unsigned* __restrict__ rows, const int* __restrict__ seg,
    const float* __restrict__ lsc,
    u16* __restrict__ Fb, float* __restrict__ Lout, float* __restrict__ realn) {
    int s = blockIdx.x;
    int tid = threadIdx.x, wave = tid >> 6, lane = tid & 63;
    int start = lower_bound(seg, TLEN, s);
    int end   = lower_bound(seg, TLEN, s + 1);
    const int lbase  = ((lane >> 2) & 3) * 512 + (lane & 3) * 8;
    const int lchunk = (lane >> 4) * 2048;
    const int chb    = (lane >> 4) * 128 + ((lane >> 2) & 3) * 32 + (lane & 3) * 8;
    float a[8] = {0,0,0,0,0,0,0,0};
    float Lacc = 0.f; int inv = 0;
    int r = start + wave;
    for (; r + 16 < end; r += 32) {
        unsigned p0 = rows[r], p1 = rows[r + 16];
        int r0 = (int)(p0 & 0x7FFFFFFFu), r1 = (int)(p1 & 0x7FFFFFFFu);
        int o0 = lbase + (r0 & 15) * 32; o0 ^= ((o0 >> 8) & 7) << 4;
        int o1 = lbase + (r1 & 15) * 32; o1 ^= ((o1 >> 8) & 7) << 4;
        uint2 v0 = *(const uint2*)(feats8 + (size_t)(r0 >> 4) * 8192 + lchunk + o0);
        uint2 v1 = *(const uint2*)(feats8 + (size_t)(r1 >> 4) * 8192 + lchunk + o1);
        if (lane == 0) {
            inv += (int)(p0 >> 31) + (int)(p1 >> 31);
            Lacc += __logf(lse_sum[r0]) + __logf(lse_sum[r1]);
        }
        a[0] += d_e4m3(v0.x);       a[1] += d_e4m3(v0.x >> 8);
        a[2] += d_e4m3(v0.x >> 16); a[3] += d_e4m3(v0.x >> 24);
        a[4] += d_e4m3(v0.y);       a[5] += d_e4m3(v0.y >> 8);
        a[6] += d_e4m3(v0.y >> 16); a[7] += d_e4m3(v0.y >> 24);
        a[0] += d_e4m3(v1.x);       a[1] += d_e4m3(v1.x >> 8);
        a[2] += d_e4m3(v1.x >> 16); a[3] += d_e4m3(v1.x >> 24);
        a[4] += d_e4m3(v1.y);       a[5] += d_e4m3(v1.y >> 8);
        a[6] += d_e4m3(v1.y >> 16); a[7] += d_e4m3(v1.y >> 24);
    }
    if (r < end) {
        unsigned p0 = rows[r];
        int r0 = (int)(p0 & 0x7FFFFFFFu);
        int o0 = lbase + (r0 & 15) * 32; o0 ^= ((o0 >> 8) & 7) << 4;
        uint2 v0 = *(const uint2*)(feats8 + (size_t)(r0 >> 4) * 8192 + lchunk + o0);
        if (lane == 0) { inv += (int)(p0 >> 31); Lacc += __logf(lse_sum[r0]); }
        a[0] += d_e4m3(v0.x);       a[1] += d_e4m3(v0.x >> 8);
        a[2] += d_e4m3(v0.x >> 16); a[3] += d_e4m3(v0.x >> 24);
        a[4] += d_e4m3(v0.y);       a[5] += d_e4m3(v0.y >> 8);
        a[6] += d_e4m3(v0.y >> 16); a[7] += d_e4m3(v0.y >> 24);
    }
    __shared__ float pF[16][512];
    __shared__ float pL[16];
    __shared__ int   pI[16];
    #pragma unroll
    for (int u = 0; u < 8; ++u) pF[wave][chb + u] = a[u];
    if (lane == 0) { pL[wave] = Lacc; pI[wave] = inv; }
    __syncthreads();
    if (tid < 512) {
        float f = 0.f;
        #pragma unroll
        for (int w = 0; w < 16; ++w) f += pF[w][tid];
        Fb[(size_t)s * CDIM + tid] = f2bf(f);
    }
    if (tid == 0) {
        float cnt = (float)(end - start);
        float Ls = 0.f; int ninv = 0;
        #pragma unroll
        for (int w = 0; w < 16; ++w) { Ls += pL[w]; ninv += pI[w]; }
        realn[s] = cnt - (float)ninv;
        Lout[s] = Ls + __expf(lsc[0]) * cnt;   // each lse = sf + log(sum)
    }
}

// ---- pooled[s,m] = (sf*Fb[s].capb[m] - L[s]) * (1/real or 0); 64x64 bf16 MFMA
//      NO LDS, NO BARRIERS: fragments loaded direct from row-major Fb/capb
//      (both 1 MB, L2-resident). ----
__global__ __launch_bounds__(256) void pooled_gemm(
    const u16* __restrict__ Fb, const u16* __restrict__ capb,
    const float* __restrict__ Lout, const float* __restrict__ realn,
    const float* __restrict__ lsc, float* __restrict__ out) {
    const int tid  = threadIdx.x;
    const int wave = tid >> 6;
    const int lane = tid & 63;
    const int col0 = blockIdx.x * 64;   // captions
    const int row0 = blockIdx.y * 64;   // segments
    const int wm = (wave >> 1) * 32;
    const int wn = (wave & 1) * 32;
    const float sf = __expf(lsc[0]);
    f32x4 acc[2][2] = {};
    const int mrow = lane & 15;
    const int quad = lane >> 4;
    // fragment for 16x16x32 bf16: lane (mrow,quad) holds row[k0+quad*8 .. +8]
    const u16* gA = Fb   + (size_t)(row0 + wm + mrow) * CDIM + quad * 8;
    const u16* gB = capb + (size_t)(col0 + wn + mrow) * CDIM + quad * 8;
    #pragma unroll
    for (int k0 = 0; k0 < CDIM; k0 += 32) {
        short8 af[2], bfr[2];
        #pragma unroll
        for (int i = 0; i < 2; ++i)
            af[i]  = *(const short8*)(gA + (size_t)(i * 16) * CDIM + k0);
        #pragma unroll
        for (int j = 0; j < 2; ++j)
            bfr[j] = *(const short8*)(gB + (size_t)(j * 16) * CDIM + k0);
        #pragma unroll
        for (int i = 0; i < 2; ++i)
            #pragma unroll
            for (int j = 0; j < 2; ++j)
                acc[i][j] = __builtin_amdgcn_mfma_f32_16x16x32_bf16(
                    af[i], bfr[j], acc[i][j], 0, 0, 0);
    }
    #pragma unroll
    for (int i = 0; i < 2; ++i) {
        #pragma unroll
        for (int r = 0; r < 4; ++r) {
            int s = row0 + wm + i * 16 + quad * 4 + r;
            float rn = realn[s];
            float dn = rn > 0.f ? 1.0f / rn : 0.0f;
            float L = Lout[s];
            #pragma unroll
            for (int j = 0; j < 2; ++j) {
                int mc = col0 + wn + j * 16 + mrow;
                out[(size_t)s * MCAP + mc] = (sf * acc[i][j][r] - L) * dn;
            }
        }
    }
    if (col0 == 0 && tid < 64) {
        int s = row0 + tid;
        float rv = realn[s];
        out[MCAP * MCAP + s] = rv;
        out[MCAP * MCAP + MCAP + s] = (rv > 0.f) ? 1.0f : 0.0f;
    }
}

extern "C" void kernel_launch(void* const* d_in, const int* in_sizes, int n_in,
                              void* d_out, int out_size, void* d_ws, size_t ws_size,
                              hipStream_t stream) {
    const float* adapter = (const float*)d_in[0];
    const float* cap     = (const float*)d_in[1];
    const float* lsc     = (const float*)d_in[2];
    const int*   v2p     = (const int*)d_in[3];
    const int*   oidx    = (const int*)d_in[4];
    const int*   ctpm    = (const int*)d_in[5];
    const int*   seg     = (const int*)d_in[6];
    float* out = (float*)d_out;

    char* ws = (char*)d_ws;
    u8*       feats8  = (u8*)(ws);                                // 67,108,864 B
    u16*      capb    = (u16*)(ws + 67108864);                    //  1,048,576 B
    u8*       Bswz    = (u8*)(ws + 68157440);                     //    524,288 B
    float*    lse_sum = (float*)(ws + 68681728);                  //    524,288 B
    int*      ptom    = (int*)(ws + 69206016);                    //    655,360 B
    unsigned* rows    = (unsigned*)(ws + 69861376);               //  1,048,576 B
    u16*      Fb      = (u16*)(ws + 70909952);                    //  1,048,576 B
    float*    Lout    = (float*)(ws + 71958528);                  //      4,096 B
    float*    realn   = (float*)(ws + 71962624);                  //      4,096 B

    hipMemsetAsync(ptom, 0xFF, (size_t)PORIG * 4, stream);        // -1

    gather_prep<<<33920, 256, 0, stream>>>(adapter, v2p, cap, oidx,
                                           feats8, capb, Bswz, ptom, lse_sum);
    lse_gemm<<<8192 + TLEN / 256, 256, 0, stream>>>(feats8, Bswz, lsc, lse_sum,
                                                    ctpm, ptom, rows);
    seg_reduce<<<MCAP, 1024, 0, stream>>>(feats8, lse_sum, rows, seg, lsc, Fb, Lout, realn);
    pooled_gemm<<<dim3(MCAP / 64, MCAP / 64), 256, 0, stream>>>(Fb, capb, Lout, realn, lsc, out);
}